// Round 12
// baseline (451.871 us; speedup 1.0000x reference)
//
#include <hip/hip_runtime.h>
#include <hip/hip_bf16.h>
#include <stdint.h>

// ---------------- problem constants ----------------
#define T_TOK  16384   // B*S
#define DMODEL 1024
#define NEXP   8
#define HDIM   2048
#define CAPSL  16512   // per-expert list capacity

// GEMM: streaming fragment design. Block = 4 waves (2M x 2N), BM=128, BN=128,
// per-wave 64x64 dual. K in 32 slices of 32. NO LDS: fragments global->VGPR from
// fragment-ordered layouts (1KB chunk per 16-row x 32-K tile, lane l reads
// chunk+16*l, coalesced). G/U PHASE-SPLIT pipeline: each slice = phase-G (16 MFMA)
// + phase-U (16 MFMA); loads issued 2 phases (~1240 cyc) before use -> covers HBM
// latency at the SAME register budget (6 sets, 96 frag regs; acc 128 AGPR).
#define BM 128
#define BN 128
#define NWORK_MAX 264            // sum_e ceil(N_e/128) <= 32768/128 + 8
#define YROWS_MAX (NWORK_MAX*BM)
#define GRID_GEMM (NWORK_MAX * 16)   // 4224 = 8 XCDs x 528

// ---------------- workspace layout (bytes) ----------------
#define OFF_COUNTS 0                   // int[8]
#define OFF_NWORK  64                  // int
#define OFF_FSUM   128                 // float[8]
#define OFF_PSUM   192                 // float[8]
#define OFF_WORK   256                 // int4[NWORK_MAX]
#define OFF_HSUM   8192                // float[NEXP*HDIM] = 64KB
#define OFF_ZERO_END 73728             // memset range [0, OFF_ZERO_END)
#define OFF_TOK    131072              // int[NEXP*CAPSL]
#define OFF_WGT    786432              // float[NEXP*CAPSL]
#define OFF_WT     2097152             // bf16 frag-ordered WgT then WuT
#define WT_ELEMS   (NEXP*HDIM*DMODEL)  // 16.7M elems
#define OFF_Y      (OFF_WT + (size_t)2*WT_ELEMS*2)          // 69,206,016
#define NEED_FAST  (OFF_Y + (size_t)YROWS_MAX*DMODEL*2)     // ~138.4 MB

typedef __attribute__((ext_vector_type(4))) float f32x4;
typedef __attribute__((ext_vector_type(8))) short bf16x8;

__device__ __forceinline__ unsigned short f2bf(float f) {
    unsigned int u = __builtin_bit_cast(unsigned int, f);
    unsigned int r = (u + 0x7fffu + ((u >> 16) & 1u)) >> 16;
    return (unsigned short)r;
}

// ---------------- 1) weight transpose -> fragment order ----------------
// W [E][D][H] f32  ->  W' bf16: chunk(nt, s) at (e*128+nt)*16384 + s*512,
// elem (q,r,j) at +q*128 + r*8 + j, value = W[e][d=s*32+q*8+j][h=nt*16+r].
__global__ __launch_bounds__(256) void wt_fragment(const float* __restrict__ wg,
                                                   const float* __restrict__ wu,
                                                   unsigned short* __restrict__ wt_out) {
    int mat = blockIdx.z;
    const float* src = mat ? wu : wg;
    unsigned short* dst = wt_out + (size_t)mat * WT_ELEMS;
    int e  = blockIdx.y;
    int kt = blockIdx.x & 15;   // d-tile of 64
    int ht = blockIdx.x >> 4;   // h-tile of 64
    __shared__ unsigned short tile[64][68];   // [dd][hh]
    const float* s = src + ((size_t)e * DMODEL + kt * 64) * HDIM + ht * 64;
    for (int u = threadIdx.x; u < 1024; u += 256) {
        int r = u >> 4, c = (u & 15) * 4;
        float4 v = *(const float4*)(s + (size_t)r * HDIM + c);
        tile[r][c + 0] = f2bf(v.x); tile[r][c + 1] = f2bf(v.y);
        tile[r][c + 2] = f2bf(v.z); tile[r][c + 3] = f2bf(v.w);
    }
    __syncthreads();
    // 512 chunks of 8 elems in this 64x64 region; 2 per thread
    for (int cc = threadIdx.x; cc < 512; cc += 256) {
        int r   = cc & 15;
        int q   = (cc >> 4) & 3;
        int sl  = (cc >> 6) & 1;
        int ntl = cc >> 7;                 // 0..3
        int hh  = ntl * 16 + r;
        int ddb = sl * 32 + q * 8;
        bf16x8 o;
        #pragma unroll
        for (int j = 0; j < 8; ++j) o[j] = (short)tile[ddb + j][hh];
        size_t idx = ((((size_t)e * 128 + ht * 4 + ntl) * 32 + kt * 2 + sl) * 4 + q) * 128
                     + r * 8;
        *(bf16x8*)(dst + idx) = o;
    }
}

// ---------------- 2) gating ----------------
__global__ __launch_bounds__(256) void gating(const float* __restrict__ x,
                                              const float* __restrict__ gw,
                                              int* counts, float* fsum, float* psum,
                                              int* tok_list, float* wgt_list) {
    __shared__ float gws_t[NEXP * DMODEL];
    __shared__ int   ch_e[64][2];
    __shared__ float ch_w[64][2];
    __shared__ float pacc[NEXP];
    __shared__ int   hist[NEXP], gbase[NEXP], cursor[NEXP];
    if (threadIdx.x < NEXP) { pacc[threadIdx.x] = 0.f; hist[threadIdx.x] = 0; cursor[threadIdx.x] = 0; }
    for (int u = threadIdx.x; u < NEXP * DMODEL; u += 256) {
        gws_t[(u & 7) * DMODEL + (u >> 3)] = gw[u];
    }
    __syncthreads();
    int wave = threadIdx.x >> 6, lane = threadIdx.x & 63;
    int tbase = blockIdx.x * 64;
    for (int it = 0; it < 16; ++it) {
        int slot = wave * 16 + it;
        int t = tbase + slot;
        float p[8] = {0, 0, 0, 0, 0, 0, 0, 0};
        #pragma unroll
        for (int j = 0; j < 16; ++j) {
            float xv = x[(size_t)t * DMODEL + j * 64 + lane];
            #pragma unroll
            for (int e2 = 0; e2 < 8; ++e2) p[e2] += xv * gws_t[e2 * DMODEL + j * 64 + lane];
        }
        #pragma unroll
        for (int off = 32; off >= 1; off >>= 1) {
            #pragma unroll
            for (int e2 = 0; e2 < 8; ++e2) p[e2] += __shfl_xor(p[e2], off);
        }
        if (lane == 0) {
            int i0 = 0; float l0 = p[0];
            #pragma unroll
            for (int e2 = 1; e2 < 8; ++e2) if (p[e2] > l0) { l0 = p[e2]; i0 = e2; }
            int i1 = -1; float l1 = -1e30f;
            #pragma unroll
            for (int e2 = 0; e2 < 8; ++e2) if (e2 != i0 && p[e2] > l1) { l1 = p[e2]; i1 = e2; }
            float a = __expf(l1 - l0);
            float w0 = 1.f / (1.f + a);
            ch_e[slot][0] = i0; ch_e[slot][1] = i1;
            ch_w[slot][0] = w0; ch_w[slot][1] = a * w0;
            atomicAdd(&hist[i0], 1); atomicAdd(&hist[i1], 1);
            float s = 0.f, ex[8];
            #pragma unroll
            for (int e2 = 0; e2 < 8; ++e2) { ex[e2] = __expf(p[e2] - l0); s += ex[e2]; }
            float inv = 1.f / s;
            #pragma unroll
            for (int e2 = 0; e2 < 8; ++e2) atomicAdd(&pacc[e2], ex[e2] * inv);
        }
    }
    __syncthreads();
    if (threadIdx.x < NEXP) {
        int h = hist[threadIdx.x];
        gbase[threadIdx.x] = atomicAdd(&counts[threadIdx.x], h);
        atomicAdd(&fsum[threadIdx.x], (float)h);
        atomicAdd(&psum[threadIdx.x], pacc[threadIdx.x]);
    }
    __syncthreads();
    if (threadIdx.x < 64) {
        int slot = threadIdx.x, t = tbase + slot;
        #pragma unroll
        for (int k2 = 0; k2 < 2; ++k2) {
            int e2 = ch_e[slot][k2];
            int pos = gbase[e2] + atomicAdd(&cursor[e2], 1);
            tok_list[e2 * CAPSL + pos] = t;
            wgt_list[e2 * CAPSL + pos] = ch_w[slot][k2];
        }
    }
}

// ---------------- 3) worklist + aux loss (parallel, 1 wave) ----------------
__global__ void build_work(const int* counts, int4* work, int* n_work,
                           const float* fsum, const float* psum, float* out_aux) {
    int lane = threadIdx.x;
    if (lane < NEXP) {
        int base_t = 0;
        for (int j = 0; j < lane; ++j) base_t += (counts[j] + BM - 1) / BM;
        int nt = (counts[lane] + BM - 1) / BM;
        for (int r = 0; r < nt; ++r)
            work[base_t + r] = make_int4(lane, r * BM, (base_t + r) * BM, 0);
        if (lane == NEXP - 1) *n_work = base_t + nt;
    }
    if (lane == 0) {
        float aux = 0.f;
        for (int e = 0; e < NEXP; ++e)
            aux += (fsum[e] / (float)T_TOK) * (psum[e] / (float)T_TOK);
        *out_aux = aux * (float)(NEXP * NEXP);
    }
}

// ---------------- 4) materialize gathered+scaled Y in fragment order ----------------
// Y' chunk(rt, s) at rt*16384 + s*512; elem (q,r,j) at +q*128+r*8+j,
// value = bf16(x[tok[slot]][s*32+q*8+j] * wgt), slot = rt*16 + r.
__global__ __launch_bounds__(256) void materialize(const float* __restrict__ x,
                                                   const int* __restrict__ tok_list,
                                                   const float* __restrict__ wgt_list,
                                                   const int* __restrict__ counts,
                                                   const int4* __restrict__ work,
                                                   const int* __restrict__ n_work,
                                                   unsigned short* __restrict__ yfrag) {
    int w = blockIdx.x; if (w >= *n_work) return;
    int4 wi = work[w];
    int e = wi.x, row0 = wi.y, yb = wi.z;
    int cnt = counts[e];
    int rtb  = (yb >> 4) + blockIdx.y * 4;   // 4 row-tiles per y-block
    int rloc = blockIdx.y * 64;
    for (int v = threadIdx.x; v < 8192; v += 256) {   // 64 rows x 1024 / 8
        int r   = v & 15;
        int q   = (v >> 4) & 3;
        int s   = (v >> 6) & 31;
        int rtl = v >> 11;                   // 0..3
        int slot = row0 + rloc + rtl * 16 + r;
        bf16x8 o;
        if (slot < cnt) {
            int t = tok_list[e * CAPSL + slot];
            float wgt = wgt_list[e * CAPSL + slot];
            const float* xp = x + (size_t)t * DMODEL + s * 32 + q * 8;
            float4 v0 = *(const float4*)xp;
            float4 v1 = *(const float4*)(xp + 4);
            o[0] = f2bf(v0.x * wgt); o[1] = f2bf(v0.y * wgt);
            o[2] = f2bf(v0.z * wgt); o[3] = f2bf(v0.w * wgt);
            o[4] = f2bf(v1.x * wgt); o[5] = f2bf(v1.y * wgt);
            o[6] = f2bf(v1.z * wgt); o[7] = f2bf(v1.w * wgt);
        } else {
            #pragma unroll
            for (int j = 0; j < 8; ++j) o[j] = 0;
        }
        *(bf16x8*)(yfrag + (size_t)(rtb + rtl) * 16384 + (s * 4 + q) * 128 + r * 8) = o;
    }
}

// ---------------- 5) streaming fused dual-GEMM: phase-split deep pipeline ----------
#define MMG(AF, GF) do {                                                               \
    __builtin_amdgcn_s_setprio(1);                                                     \
    _Pragma("unroll")                                                                  \
    for (int mi = 0; mi < 4; ++mi) {                                                   \
        _Pragma("unroll")                                                              \
        for (int ni = 0; ni < 4; ++ni)                                                 \
            accg[mi][ni] = __builtin_amdgcn_mfma_f32_16x16x32_bf16(AF[mi], GF[ni], accg[mi][ni], 0, 0, 0); \
    }                                                                                  \
    __builtin_amdgcn_s_setprio(0);                                                     \
} while (0)

#define MMU(AF, UF) do {                                                               \
    __builtin_amdgcn_s_setprio(1);                                                     \
    _Pragma("unroll")                                                                  \
    for (int mi = 0; mi < 4; ++mi) {                                                   \
        _Pragma("unroll")                                                              \
        for (int ni = 0; ni < 4; ++ni)                                                 \
            accu[mi][ni] = __builtin_amdgcn_mfma_f32_16x16x32_bf16(AF[mi], UF[ni], accu[mi][ni], 0, 0, 0); \
    }                                                                                  \
    __builtin_amdgcn_s_setprio(0);                                                     \
} while (0)

#define LD_AG(ASET, GSET, o_) do {                                                     \
    _Pragma("unroll")                                                                  \
    for (int mi = 0; mi < 4; ++mi) ASET[mi] = pA[mi][o_];                              \
    _Pragma("unroll")                                                                  \
    for (int ni = 0; ni < 4; ++ni) GSET[ni] = pG[ni][o_];                              \
    __builtin_amdgcn_sched_barrier(0);                                                 \
} while (0)

#define LD_U(USET, o_) do {                                                            \
    _Pragma("unroll")                                                                  \
    for (int ni = 0; ni < 4; ++ni) USET[ni] = pU[ni][o_];                              \
    __builtin_amdgcn_sched_barrier(0);                                                 \
} while (0)

__global__ __launch_bounds__(256, 2) void moe_gemm_fast(
        const unsigned short* __restrict__ yfrag,
        const unsigned short* __restrict__ wfrag,   // frag-ordered WgT | WuT
        const int4* __restrict__ work, const int* __restrict__ n_work,
        float* __restrict__ hsum) {
    __shared__ float red[4][64];
    // XCD-chunked decode: the 16 n-blocks of one w land on one XCD (Y L2-shared)
    int bid = blockIdx.x;
    int xcd = bid & 7, idx = bid >> 3;      // idx 0..527
    int w  = xcd * 33 + (idx >> 4);         // 0..263
    int nb = idx & 15;                      // n-block: 128 cols of H
    if (w >= *n_work) return;
    int4 wi = work[w];
    int e = wi.x, yb = wi.z;
    int tid = threadIdx.x, wave = tid >> 6, lane = tid & 63;
    int wm = wave >> 1, wn = wave & 1;      // 2M x 2N wave grid, per-wave 64x64 dual

    const bf16x8* pA[4]; const bf16x8* pG[4]; const bf16x8* pU[4];
    #pragma unroll
    for (int mi = 0; mi < 4; ++mi)
        pA[mi] = (const bf16x8*)(yfrag + (size_t)((yb >> 4) + wm * 4 + mi) * 16384 + lane * 8);
    #pragma unroll
    for (int ni = 0; ni < 4; ++ni) {
        size_t nt = (size_t)e * 128 + nb * 8 + wn * 4 + ni;
        pG[ni] = (const bf16x8*)(wfrag + nt * 16384 + lane * 8);
        pU[ni] = (const bf16x8*)(wfrag + (size_t)WT_ELEMS + nt * 16384 + lane * 8);
    }

    f32x4 accg[4][4], accu[4][4];
    #pragma unroll
    for (int mi = 0; mi < 4; ++mi)
        #pragma unroll
        for (int ni = 0; ni < 4; ++ni) {
            accg[mi][ni] = (f32x4){0.f, 0.f, 0.f, 0.f};
            accu[mi][ni] = (f32x4){0.f, 0.f, 0.f, 0.f};
        }

    // six statically-named fragment sets (rule #20), 2-deep per operand class
    bf16x8 aA[4], gA[4], uA[4], aB[4], gB[4], uB[4];

    // prologue: slice 0 into the A-parity sets
    LD_AG(aA, gA, 0);
    LD_U(uA, 0);

    // steady state: phase-G issues A/G[s+1]; phase-U issues U[s+1].
    // Every load has issue-to-use distance = 2 phases (~1240 cyc > HBM latency).
    #pragma unroll 1
    for (int s = 0; s < 30; s += 2) {
        int o1 = (s + 1) * 64, o2 = (s + 2) * 64;
        LD_AG(aB, gB, o1);
        MMG(aA, gA);
        LD_U(uB, o1);
        MMU(aA, uA);
        LD_AG(aA, gA, o2);
        MMG(aB, gB);
        LD_U(uA, o2);
        MMU(aB, uB);
    }
    // tail: slices 30 (in A-sets) and 31
    LD_AG(aB, gB, 31 * 64);
    MMG(aA, gA);
    LD_U(uB, 31 * 64);
    MMU(aA, uA);
    MMG(aB, gB);
    MMU(aB, uB);

    // epilogue: h = silu(g)*u, column-sum over the block's 128 rows
    #pragma unroll
    for (int ni = 0; ni < 4; ++ni) {
        float s = 0.f;
        #pragma unroll
        for (int mi = 0; mi < 4; ++mi)
            #pragma unroll
            for (int i = 0; i < 4; ++i) {
                float gv = accg[mi][ni][i], uv = accu[mi][ni][i];
                s += (gv / (1.f + __expf(-gv))) * uv;
            }
        s += __shfl_xor(s, 16);
        s += __shfl_xor(s, 32);
        if (lane < 16) red[wave][ni * 16 + lane] = s;
    }
    __syncthreads();
    if (tid < BN) {
        int wnc = tid >> 6, ix = tid & 63;
        float v = red[wnc][ix] + red[2 + wnc][ix];
        atomicAdd(&hsum[(size_t)e * HDIM + nb * 128 + tid], v);
    }
}

// ---------------- 5b) fallback (ws too small for ybuf) — naive, correct, unused ----
__global__ __launch_bounds__(256) void moe_slow(const float* __restrict__ x,
                                                const int* __restrict__ tok_list,
                                                const float* __restrict__ wgt_list,
                                                const int* __restrict__ counts,
                                                const float* __restrict__ wgate,
                                                const float* __restrict__ wup,
                                                float* __restrict__ hsum) {
    int e = blockIdx.x;
    int h = blockIdx.y * 256 + threadIdx.x;
    int cnt = counts[e];
    __shared__ float xs[DMODEL];
    float acc = 0.f;
    for (int i = 0; i < cnt; ++i) {
        int t = tok_list[e * CAPSL + i];
        float wv = wgt_list[e * CAPSL + i];
        for (int u = threadIdx.x; u < DMODEL; u += 256)
            xs[u] = x[(size_t)t * DMODEL + u] * wv;
        __syncthreads();
        float g = 0.f, uvv = 0.f;
        for (int k = 0; k < DMODEL; ++k) {
            float xv = xs[k];
            g   += xv * wgate[((size_t)e * DMODEL + k) * HDIM + h];
            uvv += xv * wup[((size_t)e * DMODEL + k) * HDIM + h];
        }
        acc += (g / (1.f + __expf(-g))) * uvv;
        __syncthreads();
    }
    atomicAdd(&hsum[(size_t)e * HDIM + h], acc);
}

// ---------------- 6) down-proj: out[e][:] += hsum[e][hblk] @ Wd[e][hblk] ----------
// 256 blocks (8e x 4dblk x 8hblk) -> full-device BW on the 64MB Wd read.
__global__ __launch_bounds__(256) void down_proj(const float* __restrict__ hsum,
                                                 const float* __restrict__ wd,
                                                 float* __restrict__ out) {
    int e    = blockIdx.x;
    int dblk = blockIdx.y;
    int hblk = blockIdx.z;
    __shared__ float sh[256];
    int h0 = hblk * 256;
    sh[threadIdx.x] = hsum[(size_t)e * HDIM + h0 + threadIdx.x];
    __syncthreads();
    int d = dblk * 256 + threadIdx.x;
    const float* wp = wd + ((size_t)e * HDIM + h0) * DMODEL + d;
    float acc = 0.f;
    #pragma unroll 4
    for (int h = 0; h < 256; h += 4) {
        float4 s4 = *(const float4*)&sh[h];
        acc += s4.x * wp[(size_t)(h + 0) * DMODEL];
        acc += s4.y * wp[(size_t)(h + 1) * DMODEL];
        acc += s4.z * wp[(size_t)(h + 2) * DMODEL];
        acc += s4.w * wp[(size_t)(h + 3) * DMODEL];
    }
    atomicAdd(&out[(size_t)e * DMODEL + d], acc);
}

// ---------------- host ----------------
extern "C" void kernel_launch(void* const* d_in, const int* in_sizes, int n_in,
                              void* d_out, int out_size, void* d_ws, size_t ws_size,
                              hipStream_t stream) {
    const float* x     = (const float*)d_in[0];
    const float* gw    = (const float*)d_in[1];
    const float* wgate = (const float*)d_in[2];
    const float* wup   = (const float*)d_in[3];
    const float* wdown = (const float*)d_in[4];
    float* out = (float*)d_out;
    char*  ws  = (char*)d_ws;

    int*   counts = (int*)(ws + OFF_COUNTS);
    int*   nwork  = (int*)(ws + OFF_NWORK);
    float* fsum   = (float*)(ws + OFF_FSUM);
    float* psum   = (float*)(ws + OFF_PSUM);
    int4*  workv  = (int4*)(ws + OFF_WORK);
    float* hsum   = (float*)(ws + OFF_HSUM);
    int*   tok    = (int*)(ws + OFF_TOK);
    float* wgt    = (float*)(ws + OFF_WGT);
    unsigned short* wt   = (unsigned short*)(ws + OFF_WT);
    unsigned short* ybuf = (unsigned short*)(ws + OFF_Y);

    hipMemsetAsync(d_out, 0, (size_t)out_size * sizeof(float), stream);
    hipMemsetAsync(d_ws, 0, OFF_ZERO_END, stream);

    gating<<<256, 256, 0, stream>>>(x, gw, counts, fsum, psum, tok, wgt);
    build_work<<<1, 64, 0, stream>>>(counts, workv, nwork, fsum, psum,
                                     out + (size_t)T_TOK * DMODEL);

    bool fast = ws_size >= NEED_FAST;
    if (fast) {
        wt_fragment<<<dim3(512, 8, 2), 256, 0, stream>>>(wgate, wup, wt);
        materialize<<<dim3(NWORK_MAX, 2), 256, 0, stream>>>(x, tok, wgt, counts, workv, nwork, ybuf);
        moe_gemm_fast<<<dim3(GRID_GEMM), 256, 0, stream>>>(ybuf, wt, workv, nwork, hsum);
    } else {
        moe_slow<<<dim3(NEXP, HDIM / 256), 256, 0, stream>>>(x, tok, wgt, counts,
                                                             wgate, wup, hsum);
    }

    down_proj<<<dim3(NEXP, 4, 8), 256, 0, stream>>>(hsum, wdown, out);
}

// Round 13
// 415.297 us; speedup vs baseline: 1.0881x; 1.0881x over previous
//
#include <hip/hip_runtime.h>
#include <hip/hip_bf16.h>
#include <stdint.h>

// ---------------- problem constants ----------------
#define T_TOK  16384   // B*S
#define DMODEL 1024
#define NEXP   8
#define HDIM   2048
#define CAPSL  16512   // per-expert list capacity

// GEMM: streaming fragment design (r9/r11 proven geometry). Block = 4 waves
// (2M x 2N), BM=128, BN=128, per-wave 64x64 dual. K in 32 slices of 32. NO LDS:
// fragments global->VGPR from fragment-ordered layouts (1KB chunk per 16-row x
// 32-K tile, lane l reads chunk+16*l, coalesced). 2-deep statically-named
// register dbuf. Budget note: at 2 waves/SIMD the unified VGPR+AGPR budget is
// 256/wave and this kernel uses exactly 128+128 -> ZERO slack; do not add regs.
#define BM 128
#define BN 128
#define NWORK_MAX 264            // sum_e ceil(N_e/128) <= 32768/128 + 8
#define YROWS_MAX (NWORK_MAX*BM)
#define GRID_GEMM (NWORK_MAX * 16)   // 4224 = 8 XCDs x 528

// ---------------- workspace layout (bytes) ----------------
#define OFF_COUNTS 0                   // int[8]
#define OFF_NWORK  64                  // int
#define OFF_FSUM   128                 // float[8]
#define OFF_PSUM   192                 // float[8]
#define OFF_WORK   256                 // int4[NWORK_MAX]
#define OFF_HSUM   8192                // float[NEXP*HDIM] = 64KB
#define OFF_ZERO_END 73728             // memset range [0, OFF_ZERO_END)
#define OFF_TOK    131072              // int[NEXP*CAPSL]
#define OFF_WGT    786432              // float[NEXP*CAPSL]
#define OFF_WT     2097152             // bf16 frag-ordered WgT then WuT
#define WT_ELEMS   (NEXP*HDIM*DMODEL)  // 16.7M elems
#define OFF_Y      (OFF_WT + (size_t)2*WT_ELEMS*2)          // 69,206,016
#define NEED_FAST  (OFF_Y + (size_t)YROWS_MAX*DMODEL*2)     // ~138.4 MB

typedef __attribute__((ext_vector_type(4))) float f32x4;
typedef __attribute__((ext_vector_type(8))) short bf16x8;

__device__ __forceinline__ unsigned short f2bf(float f) {
    unsigned int u = __builtin_bit_cast(unsigned int, f);
    unsigned int r = (u + 0x7fffu + ((u >> 16) & 1u)) >> 16;
    return (unsigned short)r;
}

// ---------------- 1) weight transpose -> fragment order ----------------
// W [E][D][H] f32  ->  W' bf16: chunk(nt, s) at (e*128+nt)*16384 + s*512,
// elem (q,r,j) at +q*128 + r*8 + j, value = W[e][d=s*32+q*8+j][h=nt*16+r].
__global__ __launch_bounds__(256) void wt_fragment(const float* __restrict__ wg,
                                                   const float* __restrict__ wu,
                                                   unsigned short* __restrict__ wt_out) {
    int mat = blockIdx.z;
    const float* src = mat ? wu : wg;
    unsigned short* dst = wt_out + (size_t)mat * WT_ELEMS;
    int e  = blockIdx.y;
    int kt = blockIdx.x & 15;   // d-tile of 64
    int ht = blockIdx.x >> 4;   // h-tile of 64
    __shared__ unsigned short tile[64][68];   // [dd][hh]
    const float* s = src + ((size_t)e * DMODEL + kt * 64) * HDIM + ht * 64;
    for (int u = threadIdx.x; u < 1024; u += 256) {
        int r = u >> 4, c = (u & 15) * 4;
        float4 v = *(const float4*)(s + (size_t)r * HDIM + c);
        tile[r][c + 0] = f2bf(v.x); tile[r][c + 1] = f2bf(v.y);
        tile[r][c + 2] = f2bf(v.z); tile[r][c + 3] = f2bf(v.w);
    }
    __syncthreads();
    // 512 chunks of 8 elems in this 64x64 region; 2 per thread
    for (int cc = threadIdx.x; cc < 512; cc += 256) {
        int r   = cc & 15;
        int q   = (cc >> 4) & 3;
        int sl  = (cc >> 6) & 1;
        int ntl = cc >> 7;                 // 0..3
        int hh  = ntl * 16 + r;
        int ddb = sl * 32 + q * 8;
        bf16x8 o;
        #pragma unroll
        for (int j = 0; j < 8; ++j) o[j] = (short)tile[ddb + j][hh];
        size_t idx = ((((size_t)e * 128 + ht * 4 + ntl) * 32 + kt * 2 + sl) * 4 + q) * 128
                     + r * 8;
        *(bf16x8*)(dst + idx) = o;
    }
}

// ---------------- 2) gating ----------------
__global__ __launch_bounds__(256) void gating(const float* __restrict__ x,
                                              const float* __restrict__ gw,
                                              int* counts, float* fsum, float* psum,
                                              int* tok_list, float* wgt_list) {
    __shared__ float gws_t[NEXP * DMODEL];
    __shared__ int   ch_e[64][2];
    __shared__ float ch_w[64][2];
    __shared__ float pacc[NEXP];
    __shared__ int   hist[NEXP], gbase[NEXP], cursor[NEXP];
    if (threadIdx.x < NEXP) { pacc[threadIdx.x] = 0.f; hist[threadIdx.x] = 0; cursor[threadIdx.x] = 0; }
    for (int u = threadIdx.x; u < NEXP * DMODEL; u += 256) {
        gws_t[(u & 7) * DMODEL + (u >> 3)] = gw[u];
    }
    __syncthreads();
    int wave = threadIdx.x >> 6, lane = threadIdx.x & 63;
    int tbase = blockIdx.x * 64;
    for (int it = 0; it < 16; ++it) {
        int slot = wave * 16 + it;
        int t = tbase + slot;
        float p[8] = {0, 0, 0, 0, 0, 0, 0, 0};
        #pragma unroll
        for (int j = 0; j < 16; ++j) {
            float xv = x[(size_t)t * DMODEL + j * 64 + lane];
            #pragma unroll
            for (int e2 = 0; e2 < 8; ++e2) p[e2] += xv * gws_t[e2 * DMODEL + j * 64 + lane];
        }
        #pragma unroll
        for (int off = 32; off >= 1; off >>= 1) {
            #pragma unroll
            for (int e2 = 0; e2 < 8; ++e2) p[e2] += __shfl_xor(p[e2], off);
        }
        if (lane == 0) {
            int i0 = 0; float l0 = p[0];
            #pragma unroll
            for (int e2 = 1; e2 < 8; ++e2) if (p[e2] > l0) { l0 = p[e2]; i0 = e2; }
            int i1 = -1; float l1 = -1e30f;
            #pragma unroll
            for (int e2 = 0; e2 < 8; ++e2) if (e2 != i0 && p[e2] > l1) { l1 = p[e2]; i1 = e2; }
            float a = __expf(l1 - l0);
            float w0 = 1.f / (1.f + a);
            ch_e[slot][0] = i0; ch_e[slot][1] = i1;
            ch_w[slot][0] = w0; ch_w[slot][1] = a * w0;
            atomicAdd(&hist[i0], 1); atomicAdd(&hist[i1], 1);
            float s = 0.f, ex[8];
            #pragma unroll
            for (int e2 = 0; e2 < 8; ++e2) { ex[e2] = __expf(p[e2] - l0); s += ex[e2]; }
            float inv = 1.f / s;
            #pragma unroll
            for (int e2 = 0; e2 < 8; ++e2) atomicAdd(&pacc[e2], ex[e2] * inv);
        }
    }
    __syncthreads();
    if (threadIdx.x < NEXP) {
        int h = hist[threadIdx.x];
        gbase[threadIdx.x] = atomicAdd(&counts[threadIdx.x], h);
        atomicAdd(&fsum[threadIdx.x], (float)h);
        atomicAdd(&psum[threadIdx.x], pacc[threadIdx.x]);
    }
    __syncthreads();
    if (threadIdx.x < 64) {
        int slot = threadIdx.x, t = tbase + slot;
        #pragma unroll
        for (int k2 = 0; k2 < 2; ++k2) {
            int e2 = ch_e[slot][k2];
            int pos = gbase[e2] + atomicAdd(&cursor[e2], 1);
            tok_list[e2 * CAPSL + pos] = t;
            wgt_list[e2 * CAPSL + pos] = ch_w[slot][k2];
        }
    }
}

// ---------------- 3) worklist + aux loss (parallel, 1 wave) ----------------
__global__ void build_work(const int* counts, int4* work, int* n_work,
                           const float* fsum, const float* psum, float* out_aux) {
    int lane = threadIdx.x;
    if (lane < NEXP) {
        int base_t = 0;
        for (int j = 0; j < lane; ++j) base_t += (counts[j] + BM - 1) / BM;
        int nt = (counts[lane] + BM - 1) / BM;
        for (int r = 0; r < nt; ++r)
            work[base_t + r] = make_int4(lane, r * BM, (base_t + r) * BM, 0);
        if (lane == NEXP - 1) *n_work = base_t + nt;
    }
    if (lane == 0) {
        float aux = 0.f;
        for (int e = 0; e < NEXP; ++e)
            aux += (fsum[e] / (float)T_TOK) * (psum[e] / (float)T_TOK);
        *out_aux = aux * (float)(NEXP * NEXP);
    }
}

// ---------------- 4) materialize gathered+scaled Y in fragment order ----------------
// Y' chunk(rt, s) at rt*16384 + s*512; elem (q,r,j) at +q*128+r*8+j,
// value = bf16(x[tok[slot]][s*32+q*8+j] * wgt), slot = rt*16 + r.
__global__ __launch_bounds__(256) void materialize(const float* __restrict__ x,
                                                   const int* __restrict__ tok_list,
                                                   const float* __restrict__ wgt_list,
                                                   const int* __restrict__ counts,
                                                   const int4* __restrict__ work,
                                                   const int* __restrict__ n_work,
                                                   unsigned short* __restrict__ yfrag) {
    int w = blockIdx.x; if (w >= *n_work) return;
    int4 wi = work[w];
    int e = wi.x, row0 = wi.y, yb = wi.z;
    int cnt = counts[e];
    int rtb  = (yb >> 4) + blockIdx.y * 4;   // 4 row-tiles per y-block
    int rloc = blockIdx.y * 64;
    for (int v = threadIdx.x; v < 8192; v += 256) {   // 64 rows x 1024 / 8
        int r   = v & 15;
        int q   = (v >> 4) & 3;
        int s   = (v >> 6) & 31;
        int rtl = v >> 11;                   // 0..3
        int slot = row0 + rloc + rtl * 16 + r;
        bf16x8 o;
        if (slot < cnt) {
            int t = tok_list[e * CAPSL + slot];
            float wgt = wgt_list[e * CAPSL + slot];
            const float* xp = x + (size_t)t * DMODEL + s * 32 + q * 8;
            float4 v0 = *(const float4*)xp;
            float4 v1 = *(const float4*)(xp + 4);
            o[0] = f2bf(v0.x * wgt); o[1] = f2bf(v0.y * wgt);
            o[2] = f2bf(v0.z * wgt); o[3] = f2bf(v0.w * wgt);
            o[4] = f2bf(v1.x * wgt); o[5] = f2bf(v1.y * wgt);
            o[6] = f2bf(v1.z * wgt); o[7] = f2bf(v1.w * wgt);
        } else {
            #pragma unroll
            for (int j = 0; j < 8; ++j) o[j] = 0;
        }
        *(bf16x8*)(yfrag + (size_t)(rtb + rtl) * 16384 + (s * 4 + q) * 128 + r * 8) = o;
    }
}

// ---------------- 5) streaming fused dual-GEMM: global->VGPR fragments, no LDS ----
#define MM_CLUSTER(AF, GF, UF) do {                                                    \
    __builtin_amdgcn_s_setprio(1);                                                     \
    _Pragma("unroll")                                                                  \
    for (int mi = 0; mi < 4; ++mi) {                                                   \
        _Pragma("unroll")                                                              \
        for (int ni = 0; ni < 4; ++ni) {                                               \
            accg[mi][ni] = __builtin_amdgcn_mfma_f32_16x16x32_bf16(AF[mi], GF[ni], accg[mi][ni], 0, 0, 0); \
            accu[mi][ni] = __builtin_amdgcn_mfma_f32_16x16x32_bf16(AF[mi], UF[ni], accu[mi][ni], 0, 0, 0); \
        }                                                                              \
    }                                                                                  \
    __builtin_amdgcn_s_setprio(0);                                                     \
} while (0)

__global__ __launch_bounds__(256, 2) void moe_gemm_fast(
        const unsigned short* __restrict__ yfrag,
        const unsigned short* __restrict__ wfrag,   // frag-ordered WgT | WuT
        const int4* __restrict__ work, const int* __restrict__ n_work,
        float* __restrict__ hsum) {
    __shared__ float red[4][64];
    // L2-aware XCD-chunked decode. Per XCD: idx 0..527 sweeps 4 nb-chunks of 4;
    // within a chunk all 33 w run with their 4 nb's adjacent. Sliding working set
    // = 8w x 4nb = Y 2MB + W 1MB = 3MB < 4MB L2; W chunk stays hot across the
    // whole 132-block sweep (the r11 decode thrashed: 16nb x 1w = 8MB W/expert).
    int bid = blockIdx.x;
    int xcd = bid & 7, idx = bid >> 3;      // idx 0..527
    int nbc = idx / 132;                    // 0..3 nb-chunk
    int rem = idx - nbc * 132;              // 0..131
    int w   = xcd * 33 + (rem >> 2);        // 0..263
    int nb  = nbc * 4 + (rem & 3);          // 0..15
    if (w >= *n_work) return;
    int4 wi = work[w];
    int e = wi.x, yb = wi.z;
    int tid = threadIdx.x, wave = tid >> 6, lane = tid & 63;
    int wm = wave >> 1, wn = wave & 1;      // 2M x 2N wave grid, per-wave 64x64 dual

    const bf16x8* pA[4]; const bf16x8* pG[4]; const bf16x8* pU[4];
    #pragma unroll
    for (int mi = 0; mi < 4; ++mi)
        pA[mi] = (const bf16x8*)(yfrag + (size_t)((yb >> 4) + wm * 4 + mi) * 16384 + lane * 8);
    #pragma unroll
    for (int ni = 0; ni < 4; ++ni) {
        size_t nt = (size_t)e * 128 + nb * 8 + wn * 4 + ni;
        pG[ni] = (const bf16x8*)(wfrag + nt * 16384 + lane * 8);
        pU[ni] = (const bf16x8*)(wfrag + (size_t)WT_ELEMS + nt * 16384 + lane * 8);
    }

    f32x4 accg[4][4], accu[4][4];
    #pragma unroll
    for (int mi = 0; mi < 4; ++mi)
        #pragma unroll
        for (int ni = 0; ni < 4; ++ni) {
            accg[mi][ni] = (f32x4){0.f, 0.f, 0.f, 0.f};
            accu[mi][ni] = (f32x4){0.f, 0.f, 0.f, 0.f};
        }

    // two statically-named fragment sets (rule #20: no runtime indexing)
    bf16x8 aA[4], gA[4], uA[4], aB[4], gB[4], uB[4];
    #pragma unroll
    for (int mi = 0; mi < 4; ++mi) aA[mi] = pA[mi][0];
    #pragma unroll
    for (int ni = 0; ni < 4; ++ni) { gA[ni] = pG[ni][0]; uA[ni] = pU[ni][0]; }

    #pragma unroll 1
    for (int s = 0; s < 32; s += 2) {
        {   // prefetch slice s+1 -> set B (always valid: s<=30)
            int o = (s + 1) * 64;
            #pragma unroll
            for (int mi = 0; mi < 4; ++mi) aB[mi] = pA[mi][o];
            #pragma unroll
            for (int ni = 0; ni < 4; ++ni) { gB[ni] = pG[ni][o]; uB[ni] = pU[ni][o]; }
        }
        MM_CLUSTER(aA, gA, uA);             // compute slice s (waits own loads only)
        if (s + 2 < 32) {                   // prefetch slice s+2 -> set A
            int o = (s + 2) * 64;
            #pragma unroll
            for (int mi = 0; mi < 4; ++mi) aA[mi] = pA[mi][o];
            #pragma unroll
            for (int ni = 0; ni < 4; ++ni) { gA[ni] = pG[ni][o]; uA[ni] = pU[ni][o]; }
        }
        MM_CLUSTER(aB, gB, uB);             // compute slice s+1
    }

    // epilogue: h = silu(g)*u, column-sum over the block's 128 rows
    #pragma unroll
    for (int ni = 0; ni < 4; ++ni) {
        float s = 0.f;
        #pragma unroll
        for (int mi = 0; mi < 4; ++mi)
            #pragma unroll
            for (int i = 0; i < 4; ++i) {
                float gv = accg[mi][ni][i], uv = accu[mi][ni][i];
                s += (gv / (1.f + __expf(-gv))) * uv;
            }
        s += __shfl_xor(s, 16);
        s += __shfl_xor(s, 32);
        if (lane < 16) red[wave][ni * 16 + lane] = s;
    }
    __syncthreads();
    if (tid < BN) {
        int wnc = tid >> 6, ix = tid & 63;
        float v = red[wnc][ix] + red[2 + wnc][ix];
        atomicAdd(&hsum[(size_t)e * HDIM + nb * 128 + tid], v);
    }
}

// ---------------- 5b) fallback (ws too small for ybuf) — naive, correct, unused ----
__global__ __launch_bounds__(256) void moe_slow(const float* __restrict__ x,
                                                const int* __restrict__ tok_list,
                                                const float* __restrict__ wgt_list,
                                                const int* __restrict__ counts,
                                                const float* __restrict__ wgate,
                                                const float* __restrict__ wup,
                                                float* __restrict__ hsum) {
    int e = blockIdx.x;
    int h = blockIdx.y * 256 + threadIdx.x;
    int cnt = counts[e];
    __shared__ float xs[DMODEL];
    float acc = 0.f;
    for (int i = 0; i < cnt; ++i) {
        int t = tok_list[e * CAPSL + i];
        float wv = wgt_list[e * CAPSL + i];
        for (int u = threadIdx.x; u < DMODEL; u += 256)
            xs[u] = x[(size_t)t * DMODEL + u] * wv;
        __syncthreads();
        float g = 0.f, uvv = 0.f;
        for (int k = 0; k < DMODEL; ++k) {
            float xv = xs[k];
            g   += xv * wgate[((size_t)e * DMODEL + k) * HDIM + h];
            uvv += xv * wup[((size_t)e * DMODEL + k) * HDIM + h];
        }
        acc += (g / (1.f + __expf(-g))) * uvv;
        __syncthreads();
    }
    atomicAdd(&hsum[(size_t)e * HDIM + h], acc);
}

// ---------------- 6) down-proj: out[e][:] += hsum[e][hblk] @ Wd[e][hblk] ----------
// 256 blocks (8e x 4dblk x 8hblk) -> full-device BW on the 64MB Wd read.
__global__ __launch_bounds__(256) void down_proj(const float* __restrict__ hsum,
                                                 const float* __restrict__ wd,
                                                 float* __restrict__ out) {
    int e    = blockIdx.x;
    int dblk = blockIdx.y;
    int hblk = blockIdx.z;
    __shared__ float sh[256];
    int h0 = hblk * 256;
    sh[threadIdx.x] = hsum[(size_t)e * HDIM + h0 + threadIdx.x];
    __syncthreads();
    int d = dblk * 256 + threadIdx.x;
    const float* wp = wd + ((size_t)e * HDIM + h0) * DMODEL + d;
    float acc = 0.f;
    #pragma unroll 4
    for (int h = 0; h < 256; h += 4) {
        float4 s4 = *(const float4*)&sh[h];
        acc += s4.x * wp[(size_t)(h + 0) * DMODEL];
        acc += s4.y * wp[(size_t)(h + 1) * DMODEL];
        acc += s4.z * wp[(size_t)(h + 2) * DMODEL];
        acc += s4.w * wp[(size_t)(h + 3) * DMODEL];
    }
    atomicAdd(&out[(size_t)e * DMODEL + d], acc);
}

// ---------------- host ----------------
extern "C" void kernel_launch(void* const* d_in, const int* in_sizes, int n_in,
                              void* d_out, int out_size, void* d_ws, size_t ws_size,
                              hipStream_t stream) {
    const float* x     = (const float*)d_in[0];
    const float* gw    = (const float*)d_in[1];
    const float* wgate = (const float*)d_in[2];
    const float* wup   = (const float*)d_in[3];
    const float* wdown = (const float*)d_in[4];
    float* out = (float*)d_out;
    char*  ws  = (char*)d_ws;

    int*   counts = (int*)(ws + OFF_COUNTS);
    int*   nwork  = (int*)(ws + OFF_NWORK);
    float* fsum   = (float*)(ws + OFF_FSUM);
    float* psum   = (float*)(ws + OFF_PSUM);
    int4*  workv  = (int4*)(ws + OFF_WORK);
    float* hsum   = (float*)(ws + OFF_HSUM);
    int*   tok    = (int*)(ws + OFF_TOK);
    float* wgt    = (float*)(ws + OFF_WGT);
    unsigned short* wt   = (unsigned short*)(ws + OFF_WT);
    unsigned short* ybuf = (unsigned short*)(ws + OFF_Y);

    hipMemsetAsync(d_out, 0, (size_t)out_size * sizeof(float), stream);
    hipMemsetAsync(d_ws, 0, OFF_ZERO_END, stream);

    gating<<<256, 256, 0, stream>>>(x, gw, counts, fsum, psum, tok, wgt);
    build_work<<<1, 64, 0, stream>>>(counts, workv, nwork, fsum, psum,
                                     out + (size_t)T_TOK * DMODEL);

    bool fast = ws_size >= NEED_FAST;
    if (fast) {
        wt_fragment<<<dim3(512, 8, 2), 256, 0, stream>>>(wgate, wup, wt);
        materialize<<<dim3(NWORK_MAX, 2), 256, 0, stream>>>(x, tok, wgt, counts, workv, nwork, ybuf);
        moe_gemm_fast<<<dim3(GRID_GEMM), 256, 0, stream>>>(ybuf, wt, workv, nwork, hsum);
    } else {
        moe_slow<<<dim3(NEXP, HDIM / 256), 256, 0, stream>>>(x, tok, wgt, counts,
                                                             wgate, wup, hsum);
    }

    down_proj<<<dim3(NEXP, 4, 8), 256, 0, stream>>>(hsum, wdown, out);
}